// Round 2
// baseline (6786.404 us; speedup 1.0000x reference)
//
#include <hip/hip_runtime.h>
#include <cstdint>
#include <cstddef>

// ===========================================================================
// ActionDecoder on MI355X.
// Round-2 design: 64 WGs (1/CU), WG k owns h cols [8k,8k+8) = 32 gate rows of
// W_hh, held as f16 MFMA B-fragments ENTIRELY IN VGPRS (128 VGPRs).
// Per step, per wave (no intra-WG sync at all):
//   prefetch gate inputs (GX0/P rows, next token) -> poll 64 per-producer
//   flags with one wave-wide relaxed load -> acquire fence -> A-frags direct
//   global->reg -> 32 MFMA -> per-wave LDS S scatter -> gates in f32 ->
//   2-f16 h store -> wave release-store of its own flag (own 64B line).
// No atomic RMW anywhere in the recurrence; no __syncthreads in the loop.
// ===========================================================================

typedef _Float16 f16x8 __attribute__((ext_vector_type(8)));
typedef _Float16 f16x2 __attribute__((ext_vector_type(2)));
typedef float    f32x4 __attribute__((ext_vector_type(4)));
typedef float    f32x2 __attribute__((ext_vector_type(2)));

#define TPB 256
#define NWG 64

// ---- ws layout (bytes) ----
#define WS_GX0   0          // 64*2048 f32   = 524288
#define WS_P     524288     // 512*2048 f32  = 4194304
#define WS_HN    4718592    // 64*512 f32    = 131072
#define WS_HBUF  4849664    // 2*64*512 f16  = 131072
#define WS_FLAGS 4980736    // 64 WG x 4 waves x 16B = 4096

__device__ __forceinline__ float sigm_(float x) { return 1.f / (1.f + __expf(-x)); }
__device__ __forceinline__ float tanh_(float x) {
    const float e = __expf(-2.f * fabsf(x));
    return copysignf((1.f - e) / (1.f + e), x);
}

// ---------------------------------------------------------------------------
// Generic f32 tiled GEMM: C[M,N] = A[M,K] @ B[N,K]^T (+bias1+bias2 on z==0).
// ---------------------------------------------------------------------------
__global__ void gemm_nt_bias(const float* __restrict__ A, int lda,
                             const float* __restrict__ B, int ldb,
                             float* __restrict__ C, int ldc, int K,
                             const float* __restrict__ bias1,
                             const float* __restrict__ bias2)
{
    __shared__ float As[32 * 68];
    __shared__ float Bs[32 * 68];
    const int tid = threadIdx.x;
    const int m0 = blockIdx.y * 64, n0 = blockIdx.x * 64;
    const int kchunk = K / gridDim.z;
    const int kbeg = blockIdx.z * kchunk, kend = kbeg + kchunk;
    const int tr = tid >> 4, tc = tid & 15;
    float acc[4][4] = {};

    for (int k0 = kbeg; k0 < kend; k0 += 32) {
        __syncthreads();
        #pragma unroll
        for (int idx = tid; idx < 2048; idx += TPB) {
            const int r = idx >> 5, kk = idx & 31;
            As[kk * 68 + r] = A[(size_t)(m0 + r) * lda + k0 + kk];
            Bs[kk * 68 + r] = B[(size_t)(n0 + r) * ldb + k0 + kk];
        }
        __syncthreads();
        #pragma unroll
        for (int kk = 0; kk < 32; ++kk) {
            const f32x4 a = *(const f32x4*)&As[kk * 68 + tr * 4];
            const f32x4 b = *(const f32x4*)&Bs[kk * 68 + tc * 4];
            #pragma unroll
            for (int i = 0; i < 4; ++i)
                #pragma unroll
                for (int j = 0; j < 4; ++j)
                    acc[i][j] = fmaf(a[i], b[j], acc[i][j]);
        }
    }

    const bool split = (gridDim.z > 1);
    #pragma unroll
    for (int i = 0; i < 4; ++i) {
        const int m = m0 + tr * 4 + i;
        #pragma unroll
        for (int j = 0; j < 4; ++j) {
            const int n = n0 + tc * 4 + j;
            float v = acc[i][j];
            if (blockIdx.z == 0) {
                if (bias1) v += bias1[n];
                if (bias2) v += bias2[n];
            }
            if (split) atomicAdd(&C[(size_t)m * ldc + n], v);
            else       C[(size_t)m * ldc + n] = v;
        }
    }
}

// ---------------------------------------------------------------------------
// LSTM recurrence. grid = 64 WGs x 256 threads. No RMW, no __syncthreads.
// ---------------------------------------------------------------------------
__global__ void __launch_bounds__(TPB, 1)
lstm_seq(const float* __restrict__ Whh,   // [2048,512] f32
         const float* __restrict__ GX0,   // [64,2048] f32 (ws)
         const float* __restrict__ P,     // [512,2048] f32 (ws)
         const int*   __restrict__ x2,    // [64,512]
         const int*   __restrict__ lens,  // [64]
         _Float16*    hbuf,               // [2][64*512] f16 (ws)
         float*       __restrict__ hn,    // [64,512] f32 (ws)
         unsigned int* flags)             // [64 wg][4 wv] spaced 16B
{
    __shared__ float Sw[4][16][34];       // per-wave S region (pitch even)

    const int tid = threadIdx.x, wg = blockIdx.x;
    const int lane = tid & 63, wv = tid >> 6;
    const int j0 = wg * 8;
    const int m = lane & 15, q = lane >> 4;

    // ---- one-time: B fragments (my 32 W_hh gate rows) into registers ----
    // slice row s (=MFMA n index) -> global gate row (s>>3)*512 + j0 + (s&7)
    f16x8 bfr[2][16];
    #pragma unroll
    for (int n = 0; n < 2; ++n) {
        const int s  = n * 16 + m;
        const int gr = (s >> 3) * 512 + j0 + (s & 7);
        const float* wrow = Whh + (size_t)gr * 512 + q * 8;
        #pragma unroll
        for (int ks = 0; ks < 16; ++ks) {
            const f32x4 w0 = *(const f32x4*)(wrow + ks * 32);
            const f32x4 w1 = *(const f32x4*)(wrow + ks * 32 + 4);
            f16x8 bv;
            #pragma unroll
            for (int e = 0; e < 4; ++e) {
                bv[e]     = (_Float16)w0[e];
                bv[4 + e] = (_Float16)w1[e];
            }
            bfr[n][ks] = bv;
        }
    }

    // ---- gate-thread geometry: wave wv owns batches [16wv,16wv+16) ----
    const int bl  = lane >> 2;            // 0..15 batch-local
    const int b   = wv * 16 + bl;         // batch
    const int cq  = (lane & 3) * 2;       // col offset within slice: 0,2,4,6
    const int col = j0 + cq;
    const int last = lens[b] - 1;
    const float* gx  = GX0 + (size_t)b * 2048 + col;
    const int* toks  = x2 + b * 512;
    float c0 = 0.f, c1 = 0.f;

    // ---- publish h_0 = 0 (my cells), flag := 1 ----
    { f16x2 z; z[0] = (_Float16)0.f; z[1] = (_Float16)0.f;
      *(f16x2*)(hbuf + b * 512 + col) = z; }
    unsigned int* myflag = flags + ((size_t)(wg * 4 + wv)) * 4;
    if (lane == 0)
        __hip_atomic_store(myflag, 1u, __ATOMIC_RELEASE, __HIP_MEMORY_SCOPE_AGENT);

    // wave wv polls producer flags (w=lane, v=wv): one line per lane
    const unsigned int* pollp = flags + ((size_t)(lane * 4 + wv)) * 4;

    int tok = toks[0];

    for (int t = 0; t < 512; ++t) {
        // ---- prefetch gate inputs for step t (independent of h_t) ----
        const float* pp = P + (size_t)tok * 2048 + col;
        f32x2 gxv[4], ppv[4];
        #pragma unroll
        for (int g = 0; g < 4; ++g) {
            gxv[g] = *(const f32x2*)(gx + g * 512);
            ppv[g] = *(const f32x2*)(pp + g * 512);
        }
        const int tok_next = toks[t < 511 ? t + 1 : 511];

        // ---- wait for h_t from all 64 producers (wave-parallel poll) ----
        const unsigned int tgt = (unsigned int)(t + 1);
        while (true) {
            const unsigned int v =
                __hip_atomic_load(pollp, __ATOMIC_RELAXED, __HIP_MEMORY_SCOPE_AGENT);
            if (__all((int)(v >= tgt))) break;
            __builtin_amdgcn_s_sleep(2);
        }
        __builtin_amdgcn_fence(__ATOMIC_ACQUIRE, "agent");

        const _Float16* hsrc = hbuf + (size_t)(t & 1) * (64 * 512);
        _Float16*       hdst = hbuf + (size_t)((t + 1) & 1) * (64 * 512);

        // ---- A fragments direct global->reg; 32 MFMA ----
        f16x8 af[16];
        const _Float16* ap = hsrc + (wv * 16 + m) * 512 + q * 8;
        #pragma unroll
        for (int ks = 0; ks < 16; ++ks)
            af[ks] = *(const f16x8*)(ap + ks * 32);

        f32x4 acc0 = {0.f, 0.f, 0.f, 0.f}, acc1 = {0.f, 0.f, 0.f, 0.f};
        #pragma unroll
        for (int ks = 0; ks < 16; ++ks) {
            acc0 = __builtin_amdgcn_mfma_f32_16x16x32_f16(af[ks], bfr[0][ks], acc0, 0, 0, 0);
            acc1 = __builtin_amdgcn_mfma_f32_16x16x32_f16(af[ks], bfr[1][ks], acc1, 0, 0, 0);
        }

        // ---- scatter S to per-wave LDS (D: row=(lane>>4)*4+r, col=lane&15)
        {
            const int r0 = (lane >> 4) * 4, cl = lane & 15;
            #pragma unroll
            for (int r = 0; r < 4; ++r) {
                Sw[wv][r0 + r][cl]      = acc0[r];
                Sw[wv][r0 + r][16 + cl] = acc1[r];
            }
        }
        // wave-synchronous LDS: drain ds_writes before cross-lane ds_reads
        asm volatile("s_waitcnt lgkmcnt(0)" ::: "memory");

        f32x2 sv[4];
        #pragma unroll
        for (int g = 0; g < 4; ++g)
            sv[g] = *(const f32x2*)&Sw[wv][bl][g * 8 + cq];

        // ---- gates (2 adjacent cols of one batch per thread) ----
        float hv[2];
        #pragma unroll
        for (int p = 0; p < 2; ++p) {
            const float iv = sigm_(sv[0][p] + gxv[0][p] + ppv[0][p]);
            const float fv = sigm_(sv[1][p] + gxv[1][p] + ppv[1][p]);
            const float gv = tanh_(sv[2][p] + gxv[2][p] + ppv[2][p]);
            const float ov = sigm_(sv[3][p] + gxv[3][p] + ppv[3][p]);
            float& c = p ? c1 : c0;
            c = fv * c + iv * gv;
            hv[p] = ov * tanh_(c);
        }

        f16x2 hh; hh[0] = (_Float16)hv[0]; hh[1] = (_Float16)hv[1];
        *(f16x2*)(hdst + b * 512 + col) = hh;
        if (t == last) {
            f32x2 o; o[0] = hv[0]; o[1] = hv[1];
            *(f32x2*)(hn + (size_t)b * 512 + col) = o;
        }

        // ---- publish h_{t+1}: wave-level release (vmcnt drain + wbl2) ----
        if (lane == 0)
            __hip_atomic_store(myflag, (unsigned int)(t + 2),
                               __ATOMIC_RELEASE, __HIP_MEMORY_SCOPE_AGENT);
        tok = tok_next;
    }
}

// ---------------------------------------------------------------------------
extern "C" void kernel_launch(void* const* d_in, const int* in_sizes, int n_in,
                              void* d_out, int out_size, void* d_ws, size_t ws_size,
                              hipStream_t stream)
{
    const float* x1    = (const float*)d_in[0];   // [64,1024]
    const int*   x2    = (const int*)  d_in[1];   // [64,512]
    const int*   lens  = (const int*)  d_in[2];   // [64]
    const float* emb   = (const float*)d_in[3];   // [512,128]
    const float* W_ih  = (const float*)d_in[4];   // [2048,1152]
    const float* W_hh  = (const float*)d_in[5];   // [2048,512]
    const float* b_ih  = (const float*)d_in[6];   // [2048]
    const float* b_hh  = (const float*)d_in[7];   // [2048]
    const float* W_act = (const float*)d_in[8];   // [512,512]
    const float* b_act = (const float*)d_in[9];   // [512]
    float* out = (float*)d_out;                   // [64,512]

    char* ws = (char*)d_ws;
    float*        GX0   = (float*)(ws + WS_GX0);
    float*        P     = (float*)(ws + WS_P);
    float*        hn    = (float*)(ws + WS_HN);
    _Float16*     hbuf  = (_Float16*)(ws + WS_HBUF);
    unsigned int* flags = (unsigned int*)(ws + WS_FLAGS);

    // zero flag lines, k-split accumulators (ws/out poisoned 0xAA each call)
    hipMemsetAsync(flags, 0, 4096, stream);
    hipMemsetAsync(GX0, 0, 64 * 2048 * sizeof(float), stream);
    hipMemsetAsync(out, 0, 64 * 512 * sizeof(float), stream);

    // GX0 = x1 @ W_ih[:, :1024]^T + b_ih + b_hh    (K=1024, 4-way K-split)
    gemm_nt_bias<<<dim3(32, 1, 4), TPB, 0, stream>>>(
        x1, 1024, W_ih, 1152, GX0, 2048, 1024, b_ih, b_hh);
    // P = emb @ W_ih[:, 1024:]^T                   (K=128)
    gemm_nt_bias<<<dim3(32, 8, 1), TPB, 0, stream>>>(
        emb, 128, W_ih + 1024, 1152, P, 2048, 128, nullptr, nullptr);

    // recurrence: 64 WGs (1/CU), flag-based producer/consumer sync
    lstm_seq<<<NWG, TPB, 0, stream>>>(W_hh, GX0, P, x2, lens, hbuf, hn, flags);

    // out = hn @ W_act^T + b_act                   (K=512, 4-way K-split)
    gemm_nt_bias<<<dim3(8, 1, 4), TPB, 0, stream>>>(
        hn, 512, W_act, 512, out, 512, 512, b_act, nullptr);
}

// Round 3
// 2746.742 us; speedup vs baseline: 2.4707x; 2.4707x over previous
//
#include <hip/hip_runtime.h>
#include <cstdint>
#include <cstddef>

// ===========================================================================
// ActionDecoder on MI355X — round 3.
// 64 WGs (1/CU), WG k owns h cols [8k,8k+8) = 32 gate rows of W_hh held as
// f16 MFMA B-fragments in VGPRs. All cross-WG traffic (h double-buffer +
// per-WG flags) uses RELAXED agent-scope accesses (sc1: bypass L1/L2, hit
// the Infinity Cache directly) => NO wbl2 / buffer_inv in the step loop;
// GX0/P/W stay cached in L1/L2. Release = __syncthreads (drains vmcnt) +
// tid0 flag store; acquire = control dependency on the wave-wide flag poll.
// ===========================================================================

typedef _Float16 f16x8 __attribute__((ext_vector_type(8)));
typedef _Float16 f16x2 __attribute__((ext_vector_type(2)));
typedef float    f32x4 __attribute__((ext_vector_type(4)));
typedef float    f32x2 __attribute__((ext_vector_type(2)));

#define TPB 256
#define NWG 64

// ---- ws layout (bytes) ----
#define WS_GX0   0          // 64*2048 f32   = 524288
#define WS_P     524288     // 512*2048 f32  = 4194304
#define WS_HN    4718592    // 64*512 f32    = 131072
#define WS_HBUF  4849664    // 2*64*512 f16  = 131072
#define WS_FLAGS 4980736    // 64 WG x 64B   = 4096

__device__ __forceinline__ float sigm_(float x) { return 1.f / (1.f + __expf(-x)); }
__device__ __forceinline__ float tanh_(float x) {
    const float e = __expf(-2.f * fabsf(x));
    return copysignf((1.f - e) / (1.f + e), x);
}

// device-scope (IC-coherent) relaxed accessors — no fences attached
__device__ __forceinline__ void st_ic_u32(unsigned int* p, unsigned int v) {
    __hip_atomic_store(p, v, __ATOMIC_RELAXED, __HIP_MEMORY_SCOPE_AGENT);
}
__device__ __forceinline__ unsigned int ld_ic_u32(const unsigned int* p) {
    return __hip_atomic_load(p, __ATOMIC_RELAXED, __HIP_MEMORY_SCOPE_AGENT);
}
__device__ __forceinline__ f16x8 ld_ic_f16x8(const _Float16* p) {
    union { unsigned long long u[2]; f16x8 v; } cv;
    cv.u[0] = __hip_atomic_load((const unsigned long long*)p,
                                __ATOMIC_RELAXED, __HIP_MEMORY_SCOPE_AGENT);
    cv.u[1] = __hip_atomic_load((const unsigned long long*)(p + 4),
                                __ATOMIC_RELAXED, __HIP_MEMORY_SCOPE_AGENT);
    return cv.v;
}

// ---------------------------------------------------------------------------
// Generic f32 tiled GEMM: C[M,N] = A[M,K] @ B[N,K]^T (+bias1+bias2 on z==0).
// ---------------------------------------------------------------------------
__global__ void gemm_nt_bias(const float* __restrict__ A, int lda,
                             const float* __restrict__ B, int ldb,
                             float* __restrict__ C, int ldc, int K,
                             const float* __restrict__ bias1,
                             const float* __restrict__ bias2)
{
    __shared__ float As[32 * 68];
    __shared__ float Bs[32 * 68];
    const int tid = threadIdx.x;
    const int m0 = blockIdx.y * 64, n0 = blockIdx.x * 64;
    const int kchunk = K / gridDim.z;
    const int kbeg = blockIdx.z * kchunk, kend = kbeg + kchunk;
    const int tr = tid >> 4, tc = tid & 15;
    float acc[4][4] = {};

    for (int k0 = kbeg; k0 < kend; k0 += 32) {
        __syncthreads();
        #pragma unroll
        for (int idx = tid; idx < 2048; idx += TPB) {
            const int r = idx >> 5, kk = idx & 31;
            As[kk * 68 + r] = A[(size_t)(m0 + r) * lda + k0 + kk];
            Bs[kk * 68 + r] = B[(size_t)(n0 + r) * ldb + k0 + kk];
        }
        __syncthreads();
        #pragma unroll
        for (int kk = 0; kk < 32; ++kk) {
            const f32x4 a = *(const f32x4*)&As[kk * 68 + tr * 4];
            const f32x4 b = *(const f32x4*)&Bs[kk * 68 + tc * 4];
            #pragma unroll
            for (int i = 0; i < 4; ++i)
                #pragma unroll
                for (int j = 0; j < 4; ++j)
                    acc[i][j] = fmaf(a[i], b[j], acc[i][j]);
        }
    }

    const bool split = (gridDim.z > 1);
    #pragma unroll
    for (int i = 0; i < 4; ++i) {
        const int m = m0 + tr * 4 + i;
        #pragma unroll
        for (int j = 0; j < 4; ++j) {
            const int n = n0 + tc * 4 + j;
            float v = acc[i][j];
            if (blockIdx.z == 0) {
                if (bias1) v += bias1[n];
                if (bias2) v += bias2[n];
            }
            if (split) atomicAdd(&C[(size_t)m * ldc + n], v);
            else       C[(size_t)m * ldc + n] = v;
        }
    }
}

// ---------------------------------------------------------------------------
// LSTM recurrence. grid = 64 WGs x 256 threads. One flag/WG. No fences.
// ---------------------------------------------------------------------------
__global__ void __launch_bounds__(TPB, 1)
lstm_seq(const float* __restrict__ Whh,   // [2048,512] f32
         const float* __restrict__ GX0,   // [64,2048] f32 (ws)
         const float* __restrict__ P,     // [512,2048] f32 (ws)
         const int*   __restrict__ x2,    // [64,512]
         const int*   __restrict__ lens,  // [64]
         _Float16*    hbuf,               // [2][64*512] f16 (ws, IC-resident)
         float*       __restrict__ hn,    // [64,512] f32 (ws)
         unsigned int* flags)             // [64 wg] spaced 64B
{
    __shared__ float Sw[4][16][34];       // per-wave S region

    const int tid = threadIdx.x, wg = blockIdx.x;
    const int lane = tid & 63, wv = tid >> 6;
    const int j0 = wg * 8;
    const int m = lane & 15, q = lane >> 4;

    // ---- one-time: B fragments (my 32 W_hh gate rows) into registers ----
    f16x8 bfr[2][16];
    #pragma unroll
    for (int n = 0; n < 2; ++n) {
        const int s  = n * 16 + m;
        const int gr = (s >> 3) * 512 + j0 + (s & 7);
        const float* wrow = Whh + (size_t)gr * 512 + q * 8;
        #pragma unroll
        for (int ks = 0; ks < 16; ++ks) {
            const f32x4 w0 = *(const f32x4*)(wrow + ks * 32);
            const f32x4 w1 = *(const f32x4*)(wrow + ks * 32 + 4);
            f16x8 bv;
            #pragma unroll
            for (int e = 0; e < 4; ++e) {
                bv[e]     = (_Float16)w0[e];
                bv[4 + e] = (_Float16)w1[e];
            }
            bfr[n][ks] = bv;
        }
    }

    // ---- gate-thread geometry: wave wv owns batches [16wv,16wv+16) ----
    const int bl  = lane >> 2;            // 0..15 batch-local
    const int b   = wv * 16 + bl;         // batch
    const int cq  = (lane & 3) * 2;       // col offset within slice: 0,2,4,6
    const int col = j0 + cq;
    const int last = lens[b] - 1;
    const float* gx  = GX0 + (size_t)b * 2048 + col;
    const int* toks  = x2 + b * 512;
    float c0 = 0.f, c1 = 0.f;

    // ---- publish h_0 = 0 (my cells); __syncthreads drains vmcnt ----
    st_ic_u32((unsigned int*)(hbuf + b * 512 + col), 0u);
    __syncthreads();
    unsigned int* myflag = flags + wg * 16;   // 64B spacing
    if (tid == 0) st_ic_u32(myflag, 1u);

    // wave polls all 64 WG flags: lane w -> flag of WG w
    const unsigned int* pollp = flags + lane * 16;

    int tok = toks[0];

    for (int t = 0; t < 512; ++t) {
        // ---- prefetch gate inputs for step t (cached, independent of h_t)
        const float* pp = P + (size_t)tok * 2048 + col;
        f32x2 gxv[4], ppv[4];
        #pragma unroll
        for (int g = 0; g < 4; ++g) {
            gxv[g] = *(const f32x2*)(gx + g * 512);
            ppv[g] = *(const f32x2*)(pp + g * 512);
        }
        const int tok_next = toks[t < 511 ? t + 1 : 511];

        // ---- wait for h_t from all 64 WGs (wave-parallel flag poll) ----
        const unsigned int tgt = (unsigned int)(t + 1);
        while (true) {
            const unsigned int v = ld_ic_u32(pollp);
            if (__all((int)(v >= tgt))) break;
        }
        asm volatile("" ::: "memory");    // compiler barrier only

        const _Float16* hsrc = hbuf + (size_t)(t & 1) * (64 * 512);
        _Float16*       hdst = hbuf + (size_t)((t + 1) & 1) * (64 * 512);

        // ---- A fragments direct IC->reg; 32 MFMA ----
        f16x8 af[16];
        const _Float16* ap = hsrc + (wv * 16 + m) * 512 + q * 8;
        #pragma unroll
        for (int ks = 0; ks < 16; ++ks)
            af[ks] = ld_ic_f16x8(ap + ks * 32);

        f32x4 acc0 = {0.f, 0.f, 0.f, 0.f}, acc1 = {0.f, 0.f, 0.f, 0.f};
        #pragma unroll
        for (int ks = 0; ks < 16; ++ks) {
            acc0 = __builtin_amdgcn_mfma_f32_16x16x32_f16(af[ks], bfr[0][ks], acc0, 0, 0, 0);
            acc1 = __builtin_amdgcn_mfma_f32_16x16x32_f16(af[ks], bfr[1][ks], acc1, 0, 0, 0);
        }

        // ---- scatter S to per-wave LDS (D: row=(lane>>4)*4+r, col=lane&15)
        {
            const int r0 = (lane >> 4) * 4, cl = lane & 15;
            #pragma unroll
            for (int r = 0; r < 4; ++r) {
                Sw[wv][r0 + r][cl]      = acc0[r];
                Sw[wv][r0 + r][16 + cl] = acc1[r];
            }
        }
        asm volatile("s_waitcnt lgkmcnt(0)" ::: "memory");  // wave-local LDS

        f32x2 sv[4];
        #pragma unroll
        for (int g = 0; g < 4; ++g)
            sv[g] = *(const f32x2*)&Sw[wv][bl][g * 8 + cq];

        // ---- gates (2 adjacent cols of one batch per thread) ----
        float hv[2];
        #pragma unroll
        for (int p = 0; p < 2; ++p) {
            const float iv = sigm_(sv[0][p] + gxv[0][p] + ppv[0][p]);
            const float fv = sigm_(sv[1][p] + gxv[1][p] + ppv[1][p]);
            const float gv = tanh_(sv[2][p] + gxv[2][p] + ppv[2][p]);
            const float ov = sigm_(sv[3][p] + gxv[3][p] + ppv[3][p]);
            float& c = p ? c1 : c0;
            c = fv * c + iv * gv;
            hv[p] = ov * tanh_(c);
        }

        f16x2 hh; hh[0] = (_Float16)hv[0]; hh[1] = (_Float16)hv[1];
        st_ic_u32((unsigned int*)(hdst + b * 512 + col),
                  __builtin_bit_cast(unsigned int, hh));
        if (t == last) {
            f32x2 o; o[0] = hv[0]; o[1] = hv[1];
            *(f32x2*)(hn + (size_t)b * 512 + col) = o;
        }

        // ---- release: __syncthreads drains each wave's vmcnt, then flag ----
        __syncthreads();
        if (tid == 0) st_ic_u32(myflag, (unsigned int)(t + 2));
        tok = tok_next;
    }
}

// ---------------------------------------------------------------------------
extern "C" void kernel_launch(void* const* d_in, const int* in_sizes, int n_in,
                              void* d_out, int out_size, void* d_ws, size_t ws_size,
                              hipStream_t stream)
{
    const float* x1    = (const float*)d_in[0];   // [64,1024]
    const int*   x2    = (const int*)  d_in[1];   // [64,512]
    const int*   lens  = (const int*)  d_in[2];   // [64]
    const float* emb   = (const float*)d_in[3];   // [512,128]
    const float* W_ih  = (const float*)d_in[4];   // [2048,1152]
    const float* W_hh  = (const float*)d_in[5];   // [2048,512]
    const float* b_ih  = (const float*)d_in[6];   // [2048]
    const float* b_hh  = (const float*)d_in[7];   // [2048]
    const float* W_act = (const float*)d_in[8];   // [512,512]
    const float* b_act = (const float*)d_in[9];   // [512]
    float* out = (float*)d_out;                   // [64,512]

    char* ws = (char*)d_ws;
    float*        GX0   = (float*)(ws + WS_GX0);
    float*        P     = (float*)(ws + WS_P);
    float*        hn    = (float*)(ws + WS_HN);
    _Float16*     hbuf  = (_Float16*)(ws + WS_HBUF);
    unsigned int* flags = (unsigned int*)(ws + WS_FLAGS);

    // zero flags + k-split accumulators (ws/out poisoned 0xAA each call)
    hipMemsetAsync(flags, 0, 4096, stream);
    hipMemsetAsync(GX0, 0, 64 * 2048 * sizeof(float), stream);
    hipMemsetAsync(out, 0, 64 * 512 * sizeof(float), stream);

    // GX0 = x1 @ W_ih[:, :1024]^T + b_ih + b_hh    (K=1024, 4-way K-split)
    gemm_nt_bias<<<dim3(32, 1, 4), TPB, 0, stream>>>(
        x1, 1024, W_ih, 1152, GX0, 2048, 1024, b_ih, b_hh);
    // P = emb @ W_ih[:, 1024:]^T                   (K=128)
    gemm_nt_bias<<<dim3(32, 8, 1), TPB, 0, stream>>>(
        emb, 128, W_ih + 1024, 1152, P, 2048, 128, nullptr, nullptr);

    // recurrence: 64 WGs (1/CU), IC-coherent data + per-WG flags
    lstm_seq<<<NWG, TPB, 0, stream>>>(W_hh, GX0, P, x2, lens, hbuf, hn, flags);

    // out = hn @ W_act^T + b_act                   (K=512, 4-way K-split)
    gemm_nt_bias<<<dim3(8, 1, 4), TPB, 0, stream>>>(
        hn, 512, W_act, 512, out, 512, 512, b_act, nullptr);
}